// Round 4
// baseline (196.994 us; speedup 1.0000x reference)
//
#include <hip/hip_runtime.h>
#include <stdint.h>

// ---------------------------------------------------------------------------
// SNN EMNIST forward: T=10, B=4096, IN=784, HID=256, NCLS=47
// R15: fuse the threefry spikegen INTO the R14 gemm structure.
// R14 profile: spikegen_k 68us @ VALUBusy 82% / MfmaUtil 0, while the gemm's
// VALU sits idle (13% in R13). Hash issue (~138 instr/hash measured) is the
// true floor; inside the dbuf gemm, MFMA (~600 cyc/SIMD/slab) + B staging
// hide entirely under the ~6K cyc/SIMD/slab of hash. Per slab: issue B[kw+1]
// global_load_lds -> hash A[kw+1] bits (verbatim spikegen compare expr) ->
// ds_write frags to nxt -> 60 MFMA/wave from cur -> one barrier. Spike
// workspace + kernel deleted. Bits, frag mapping, accumulation order all
// unchanged -> I_all bitwise identical -> absmax stays 4.882812e-4.
// splitk/scanout unchanged for attribution.
// ---------------------------------------------------------------------------

#define T_STEPS 10
#define BATCH   4096
#define IN_DIM  784
#define HID     256
#define NCLS    47
#define NROWS   (T_STEPS * BATCH)        // 40960
#define KWORDS  25                       // ceil(784/32)
#define KPAD    800                      // 25*32
#define M_TILE  160

// d_ws layout (bytes):
//   [0, 41943040)          I_all  : float [40960][256]
//   [46039040, ...)        W1{hi,mid,lo}T : bf16 [256][800], 409600 B each
#define WS_IALL_OFF 0u
#define WS_W1HI_OFF 46039040u
#define WS_W1MD_OFF (46039040u + 409600u)
#define WS_W1LO_OFF (46039040u + 819200u)

typedef __attribute__((ext_vector_type(8))) short    bf16x8;
typedef __attribute__((ext_vector_type(4))) float    f32x4;
typedef __attribute__((ext_vector_type(4))) uint32_t u32x4;

__device__ __forceinline__ uint32_t rotl32(uint32_t x, uint32_t r) {
    return __builtin_amdgcn_alignbit(x, x, 32u - r);
}

// JAX threefry2x32, key=(0,42), partitionable scheme: out = o0^o1, x0=0, x1=i.
__device__ __forceinline__ uint32_t tf_hash(uint32_t lo) {
    const uint32_t ks1 = 42u;
    const uint32_t ks2 = 0x1BD11BDAu ^ 42u;
    uint32_t x0 = 0u;
    uint32_t x1 = lo + ks1;
#define TF_RND(r) { x0 += x1; x1 = rotl32(x1, r); x1 ^= x0; }
    TF_RND(13) TF_RND(15) TF_RND(26) TF_RND(6)
    x0 += ks1; x1 += ks2 + 1u;
    TF_RND(17) TF_RND(29) TF_RND(16) TF_RND(24)
    x0 += ks2; x1 += 2u;                       // ks0 == 0
    TF_RND(13) TF_RND(15) TF_RND(26) TF_RND(6)
    x1 += ks1 + 3u;                            // x0 += ks0 is a no-op
    TF_RND(17) TF_RND(29) TF_RND(16) TF_RND(24)
    x0 += ks1; x1 += ks2 + 4u;
    TF_RND(13) TF_RND(15) TF_RND(26) TF_RND(6)
    x0 += ks2; x1 += 5u;                       // ks0 == 0
#undef TF_RND
    return x0 ^ x1;
}

// 8 consecutive spike bits for element base ib (= row*784 + k0), pixel ptr xp.
// Bit p = spike at ib+p. Identical compare expr / bit order to the verified
// spikegen path. The 8 hash chains are independent -> ILP 8; x-load latency
// hides under the ~1.2K-cycle hash core (loads don't feed the rounds).
__device__ __forceinline__ uint32_t hash8(uint32_t ib, const float* xp) {
    float4 xa = *(const float4*)xp;
    float4 xb = *(const float4*)(xp + 4);
    uint32_t bits = 0u;
    bits |= ((float)(tf_hash(ib + 0u) >> 9) < xa.x * 8388608.0f) ? 1u   : 0u;
    bits |= ((float)(tf_hash(ib + 1u) >> 9) < xa.y * 8388608.0f) ? 2u   : 0u;
    bits |= ((float)(tf_hash(ib + 2u) >> 9) < xa.z * 8388608.0f) ? 4u   : 0u;
    bits |= ((float)(tf_hash(ib + 3u) >> 9) < xa.w * 8388608.0f) ? 8u   : 0u;
    bits |= ((float)(tf_hash(ib + 4u) >> 9) < xb.x * 8388608.0f) ? 16u  : 0u;
    bits |= ((float)(tf_hash(ib + 5u) >> 9) < xb.y * 8388608.0f) ? 32u  : 0u;
    bits |= ((float)(tf_hash(ib + 6u) >> 9) < xb.z * 8388608.0f) ? 64u  : 0u;
    bits |= ((float)(tf_hash(ib + 7u) >> 9) < xb.w * 8388608.0f) ? 128u : 0u;
    return bits;
}

// ---------------------------------------------------------------------------
// Kernel B0: split W1 (f32 [784][256]) into transposed bf16 hi/mid/lo
// [256][800]. EXACT: hi+mid+lo == w bitwise.
// ---------------------------------------------------------------------------
__global__ __launch_bounds__(256) void splitk_k(
        const float* __restrict__ W1, ushort* __restrict__ hiT,
        ushort* __restrict__ midT, ushort* __restrict__ loT) {
    int n = blockIdx.x;                  // 0..255
    for (int k = threadIdx.x; k < KPAD; k += 256) {
        float w = (k < IN_DIM) ? W1[k * HID + n] : 0.0f;
        uint32_t u = __float_as_uint(w);
        uint32_t hb = (u + 0x7FFFu + ((u >> 16) & 1u)) >> 16;    // RNE to bf16
        float hf = __uint_as_float(hb << 16);
        float r1 = w - hf;                                       // exact
        uint32_t u1 = __float_as_uint(r1);
        uint32_t mb = (u1 + 0x7FFFu + ((u1 >> 16) & 1u)) >> 16;  // RNE
        float mf2 = __uint_as_float(mb << 16);
        float r2 = r1 - mf2;                                     // exact
        uint32_t u2 = __float_as_uint(r2);
        uint32_t lb = (u2 + 0x7FFFu + ((u2 >> 16) & 1u)) >> 16;  // exact fit
        hiT [n * KPAD + k] = (ushort)hb;
        midT[n * KPAD + k] = (ushort)mb;
        loT [n * KPAD + k] = (ushort)lb;
    }
}

// ---------------------------------------------------------------------------
// Fused spikegen + GEMM: I_all = bernoulli(x) @ W1 + b1 (3-plane exact bf16).
// Block: 160 rows x 256 cols, 512 threads = 8 waves (2M x 4N), wave = 80x64
// = 5x4 tiles of 16x16x32. Grid 256 = 1 block/CU. A and B double-buffered;
// one __syncthreads per slab: issue B[kw+1] global_load_lds, hash+write
// A[kw+1] frags into buffer nxt, compute 60 MFMA/wave from buffer cur,
// barrier (implicit vmcnt/lgkm drain), flip. XOR-swizzled 16B quarters keep
// ds_read_b128 <=2-way. Accum order identical to R14.
// LDS: A bufs [0,20480), B bufs 20480 + c*49152 {hi+0, mid+16384, lo+32768}.
// ---------------------------------------------------------------------------
#define LDS_B0  20480
#define B_BUFSZ 49152
#define A_BUFSZ 10240

__global__ __launch_bounds__(512, 2) void fused_gemm_k(
        const ushort* __restrict__ hiT, const ushort* __restrict__ midT,
        const ushort* __restrict__ loT, const float* __restrict__ b1,
        const float* __restrict__ x, float* __restrict__ I_all) {
    __shared__ __align__(16) char lds[118784];   // 116 KB, 1 block/CU

    const int tid = threadIdx.x;
    const int l   = tid & 63;
    const int wv  = tid >> 6;        // 0..7
    const int wm  = wv >> 2;         // 0..1 (M half)
    const int wn  = wv & 3;          // 0..3 (N quarter)
    const int m0  = blockIdx.x * M_TILE;

    f32x4 acc[5][4] = {};

    // fragment read addressing (shared swizzle sig for A and B)
    const int q   = l >> 4;
    const int sig = q ^ (l & 3) ^ ((l >> 2) & 3);
    const int a_rd = wm * 5120 + ((l & 15) << 6) + (sig << 4);      // in A buf
    const int b_rd = (((wn << 6) + (l & 15)) << 6) + (sig << 4);    // in plane

    // ---- B staging: 1024 slots of 16B per plane, 2 per thread ----
    const ushort* hi_p[2];
    const ushort* md_p[2];
    const ushort* lo_p[2];
    int bdst[2];
#pragma unroll
    for (int i = 0; i < 2; ++i) {
        int s  = (i << 9) + tid;
        int n  = s >> 2;
        int qs = s & 3;
        int qd = qs ^ (n & 3) ^ ((n >> 2) & 3);
        size_t eoff = (size_t)n * KPAD + ((size_t)qd << 3);
        hi_p[i] = hiT  + eoff;
        md_p[i] = midT + eoff;
        lo_p[i] = loT  + eoff;
        bdst[i] = ((i << 9) + (wv << 6)) << 4;    // wave-uniform base
    }

    // ---- A expansion: 640 tasks (row 0..159 x eq 0..3); task1 = tid for
    // all, task2 = 512+tid for tid<128 (wave-uniform: waves 0,1).
    const int  eq   = tid & 3;
    const int  r1   = tid >> 2;                    // 0..127
    const bool has2 = (tid < 128);
    const int  r2   = 128 + (tid >> 2);            // valid only if has2
    const int  ea1  = (r1 << 6) + ((eq ^ (r1 & 3) ^ ((r1 >> 2) & 3)) << 4);
    const int  ea2  = (r2 << 6) + ((eq ^ (r2 & 3) ^ ((r2 >> 2) & 3)) << 4);

    // per-task hash/pixel bases (k-offset koff added per slab)
    const int rg1 = m0 + r1;
    const int rg2 = m0 + (has2 ? r2 : r1);
    const float*   xp1 = x + (size_t)(rg1 & (BATCH - 1)) * IN_DIM + (eq << 3);
    const float*   xp2 = x + (size_t)(rg2 & (BATCH - 1)) * IN_DIM + (eq << 3);
    const uint32_t ib1 = (uint32_t)rg1 * (uint32_t)IN_DIM + (uint32_t)(eq << 3);
    const uint32_t ib2 = (uint32_t)rg2 * (uint32_t)IN_DIM + (uint32_t)(eq << 3);

#define SPIKE_FRAG_STORE(byt, dst) { \
    u32x4 v_; \
    v_.x = (((byt) & 1u)   ? 0x3F80u : 0u) | (((byt) & 2u)   ? 0x3F800000u : 0u); \
    v_.y = (((byt) & 4u)   ? 0x3F80u : 0u) | (((byt) & 8u)   ? 0x3F800000u : 0u); \
    v_.z = (((byt) & 16u)  ? 0x3F80u : 0u) | (((byt) & 32u)  ? 0x3F800000u : 0u); \
    v_.w = (((byt) & 64u)  ? 0x3F80u : 0u) | (((byt) & 128u) ? 0x3F800000u : 0u); \
    *(u32x4*)(dst) = v_; }

#define STAGE_B(koff, bbase) \
    _Pragma("unroll") \
    for (int i = 0; i < 2; ++i) { \
        __builtin_amdgcn_global_load_lds( \
            (const __attribute__((address_space(1))) void*)(hi_p[i] + (koff)), \
            (__attribute__((address_space(3))) void*)(lds + (bbase) + bdst[i]), \
            16, 0, 0); \
        __builtin_amdgcn_global_load_lds( \
            (const __attribute__((address_space(1))) void*)(md_p[i] + (koff)), \
            (__attribute__((address_space(3))) void*)(lds + (bbase) + 16384 + bdst[i]), \
            16, 0, 0); \
        __builtin_amdgcn_global_load_lds( \
            (const __attribute__((address_space(1))) void*)(lo_p[i] + (koff)), \
            (__attribute__((address_space(3))) void*)(lds + (bbase) + 32768 + bdst[i]), \
            16, 0, 0); \
    }

    // ---- prologue: stage slab 0 into buffers 0 (kw=0 has no tail) ----
    STAGE_B(0, LDS_B0)
    {
        uint32_t byt1 = hash8(ib1, xp1);
        SPIKE_FRAG_STORE(byt1, lds + ea1)
        if (has2) {
            uint32_t byt2 = hash8(ib2, xp2);
            SPIKE_FRAG_STORE(byt2, lds + ea2)
        }
    }
    __syncthreads();

    int cur = 0;
#pragma unroll 1
    for (int kw = 0; kw < KWORDS; ++kw) {
        const int nxt = cur ^ 1;
        if (kw < KWORDS - 1) {
            // issue next slab's B loads + hash next slab's A frags into nxt
            const int koff = (kw + 1) << 5;           // +32 elems per slab
            STAGE_B(koff, LDS_B0 + nxt * B_BUFSZ)
            const bool tail = (kw + 1 == KWORDS - 1); // slab 24: k>=784 -> 0
            uint32_t byt1 = 0u, byt2 = 0u;
            if (!(tail && eq >= 2)) {
                byt1 = hash8(ib1 + koff, xp1 + koff);
                if (has2) byt2 = hash8(ib2 + koff, xp2 + koff);
            }
            SPIKE_FRAG_STORE(byt1, lds + nxt * A_BUFSZ + ea1)
            if (has2) SPIKE_FRAG_STORE(byt2, lds + nxt * A_BUFSZ + ea2)
        }

        // --- compute slab kw from buffer cur: 5x4x3 = 60 MFMA / wave ---
        const char* A = lds + cur * A_BUFSZ;
        const char* B = lds + LDS_B0 + cur * B_BUFSZ;
        bf16x8 af[5];
#pragma unroll
        for (int mt = 0; mt < 5; ++mt)
            af[mt] = *(const bf16x8*)(A + a_rd + (mt << 10));
#pragma unroll
        for (int nt = 0; nt < 4; ++nt) {
            bf16x8 bh = *(const bf16x8*)(B + b_rd + (nt << 10));
            bf16x8 bm = *(const bf16x8*)(B + 16384 + b_rd + (nt << 10));
            bf16x8 bl = *(const bf16x8*)(B + 32768 + b_rd + (nt << 10));
#pragma unroll
            for (int mt = 0; mt < 5; ++mt) {
                acc[mt][nt] = __builtin_amdgcn_mfma_f32_16x16x32_bf16(af[mt], bh, acc[mt][nt], 0, 0, 0);
                acc[mt][nt] = __builtin_amdgcn_mfma_f32_16x16x32_bf16(af[mt], bm, acc[mt][nt], 0, 0, 0);
                acc[mt][nt] = __builtin_amdgcn_mfma_f32_16x16x32_bf16(af[mt], bl, acc[mt][nt], 0, 0, 0);
            }
        }

        __syncthreads();   // drains vmcnt (B nxt) + lgkm (A nxt); flip safe
        cur = nxt;
    }
#undef STAGE_B
#undef SPIKE_FRAG_STORE

    // --- epilogue: acc -> I_all (+ b1) ---
    const int c0 = l & 15;
    float b1v[4];
#pragma unroll
    for (int nt = 0; nt < 4; ++nt)
        b1v[nt] = b1[(wn << 6) + (nt << 4) + c0];
#pragma unroll
    for (int mt = 0; mt < 5; ++mt) {
#pragma unroll
        for (int nt = 0; nt < 4; ++nt) {
            int col = (wn << 6) + (nt << 4) + c0;
#pragma unroll
            for (int r = 0; r < 4; ++r) {
                int row = m0 + wm * 80 + (mt << 4) + (q << 2) + r;
                I_all[(size_t)row * HID + col] = acc[mt][nt][r] + b1v[nt];
            }
        }
    }
}

// ---------------------------------------------------------------------------
// Fused LIF scan + readout: per block, 4 batch rows (1024 blocks = 4/CU).
// Phase 1: thread h scans 4 rows over t (exact reference op order) -> g in
// LDS. Phase 2: wave wv -> row b0+wv, lane c<47: out = sum_h g[b][h]*Wr[h][c]
// (+ br*(1-2^-10)), h ascending — identical fmaf chain to R14.
// ---------------------------------------------------------------------------
__global__ __launch_bounds__(256) void scanout_k(
        const float* __restrict__ I_all, const float* __restrict__ Wr,
        const float* __restrict__ br, float* __restrict__ out) {
    __shared__ float gl[4 * 256];        // 4 KB
    const int tid = threadIdx.x;
    const int b0  = blockIdx.x << 2;

#pragma unroll
    for (int b = 0; b < 4; ++b) {
        const float* p = I_all + ((size_t)(b0 + b) << 8) + tid;
        float v = 0.f, ga = 0.f, wt = 0.0009765625f;   // 2^-10
#pragma unroll
        for (int t = 0; t < T_STEPS; ++t) {
            float I = p[(size_t)t * BATCH * HID];
            v = v + (I - v) * 0.5f;
            if (v >= 1.0f) { ga += wt; v = 0.f; }
            wt += wt;
        }
        gl[(b << 8) + tid] = ga;
    }
    __syncthreads();

    const int wv = tid >> 6;             // wave -> batch row b0+wv
    const int c  = tid & 63;
    if (c >= NCLS) return;
    const float* gb = &gl[wv << 8];
    float acc = 0.f;
    for (int h4 = 0; h4 < 64; ++h4) {
        float w0 = Wr[((h4 << 2) + 0) * NCLS + c];
        float w1 = Wr[((h4 << 2) + 1) * NCLS + c];
        float w2 = Wr[((h4 << 2) + 2) * NCLS + c];
        float w3 = Wr[((h4 << 2) + 3) * NCLS + c];
        float4 gg = *(const float4*)&gb[h4 << 2];
        acc = fmaf(gg.x, w0, acc);
        acc = fmaf(gg.y, w1, acc);
        acc = fmaf(gg.z, w2, acc);
        acc = fmaf(gg.w, w3, acc);
    }
    float brv = br[c] * 0.9990234375f;
    out[(b0 + wv) * NCLS + c] = acc + brv;
}

extern "C" void kernel_launch(void* const* d_in, const int* in_sizes, int n_in,
                              void* d_out, int out_size, void* d_ws, size_t ws_size,
                              hipStream_t stream) {
    const float* x  = (const float*)d_in[0];
    const float* W1 = (const float*)d_in[1];
    const float* b1 = (const float*)d_in[2];
    const float* Wr = (const float*)d_in[3];
    const float* br = (const float*)d_in[4];
    float* out = (float*)d_out;

    float*  I_all = (float*) ((char*)d_ws + WS_IALL_OFF);
    ushort* w1hi  = (ushort*)((char*)d_ws + WS_W1HI_OFF);
    ushort* w1md  = (ushort*)((char*)d_ws + WS_W1MD_OFF);
    ushort* w1lo  = (ushort*)((char*)d_ws + WS_W1LO_OFF);

    splitk_k<<<HID, 256, 0, stream>>>(W1, w1hi, w1md, w1lo);
    fused_gemm_k<<<NROWS / M_TILE, 512, 0, stream>>>(w1hi, w1md, w1lo, b1, x, I_all);
    scanout_k<<<BATCH / 4, 256, 0, stream>>>(I_all, Wr, br, out);
}

// Round 5
// 185.035 us; speedup vs baseline: 1.0646x; 1.0646x over previous
//
#include <hip/hip_runtime.h>
#include <stdint.h>

// ---------------------------------------------------------------------------
// SNN EMNIST forward: T=10, B=4096, IN=784, HID=256, NCLS=47
// R16: fix the R15 hash<->MFMA serialization + hash imbalance.
// R15 PMC: VALUBusy 53% x 124us = 66us = exactly the hash issue; the other
// 58us = the gemm phase, fully exposed. Cause: ds_read(cur) cannot be
// hoisted above ds_write(nxt) (no LDS alias proof) -> hash then MFMA run
// serially per slab; plus 640 hash8 tasks / 512 threads gave waves 0-1
// double work (barrier syncs to slowest SIMD: 6624 vs 5520 cyc).
// Changes (scheduling only, dataflow identical):
//  1. Slab body reordered: STAGE_B -> preload ALL 17 frags (ds_read) ->
//     hash -> ds_write(nxt) -> 60 MFMA. Reads issue at interval start
//     (latency hides under hash); MFMAs are register-only and free to
//     interleave with hash VALU.
//  2. Hash re-granularized to hash2 tasks: 2560/slab = exactly 5/thread
//     (10 hashes), ds_write_b32 each, same bit->bf16 frag bytes.
// Accum order unchanged (kw asc x hi,mid,lo) -> I_all bitwise identical ->
// absmax stays 4.882812e-4. splitk/scanout unchanged.
// ---------------------------------------------------------------------------

#define T_STEPS 10
#define BATCH   4096
#define IN_DIM  784
#define HID     256
#define NCLS    47
#define NROWS   (T_STEPS * BATCH)        // 40960
#define KWORDS  25                       // ceil(784/32)
#define KPAD    800                      // 25*32
#define M_TILE  160

// d_ws layout (bytes):
//   [0, 41943040)          I_all  : float [40960][256]
//   [46039040, ...)        W1{hi,mid,lo}T : bf16 [256][800], 409600 B each
#define WS_IALL_OFF 0u
#define WS_W1HI_OFF 46039040u
#define WS_W1MD_OFF (46039040u + 409600u)
#define WS_W1LO_OFF (46039040u + 819200u)

typedef __attribute__((ext_vector_type(8))) short    bf16x8;
typedef __attribute__((ext_vector_type(4))) float    f32x4;
typedef __attribute__((ext_vector_type(4))) uint32_t u32x4;

__device__ __forceinline__ uint32_t rotl32(uint32_t x, uint32_t r) {
    return __builtin_amdgcn_alignbit(x, x, 32u - r);
}

// JAX threefry2x32, key=(0,42), partitionable scheme: out = o0^o1, x0=0, x1=i.
__device__ __forceinline__ uint32_t tf_hash(uint32_t lo) {
    const uint32_t ks1 = 42u;
    const uint32_t ks2 = 0x1BD11BDAu ^ 42u;
    uint32_t x0 = 0u;
    uint32_t x1 = lo + ks1;
#define TF_RND(r) { x0 += x1; x1 = rotl32(x1, r); x1 ^= x0; }
    TF_RND(13) TF_RND(15) TF_RND(26) TF_RND(6)
    x0 += ks1; x1 += ks2 + 1u;
    TF_RND(17) TF_RND(29) TF_RND(16) TF_RND(24)
    x0 += ks2; x1 += 2u;                       // ks0 == 0
    TF_RND(13) TF_RND(15) TF_RND(26) TF_RND(6)
    x1 += ks1 + 3u;                            // x0 += ks0 is a no-op
    TF_RND(17) TF_RND(29) TF_RND(16) TF_RND(24)
    x0 += ks1; x1 += ks2 + 4u;
    TF_RND(13) TF_RND(15) TF_RND(26) TF_RND(6)
    x0 += ks2; x1 += 5u;                       // ks0 == 0
#undef TF_RND
    return x0 ^ x1;
}

// Two consecutive spike bits -> one packed u32 (2 bf16 lanes). Identical
// compare expr / bf16 encoding to the verified path: even bit -> low bf16
// (0x3F80), odd bit -> high bf16 (0x3F800000).
__device__ __forceinline__ uint32_t hash2(uint32_t ib, const float* xp) {
    float2 xx = *(const float2*)xp;
    uint32_t w = 0u;
    w |= ((float)(tf_hash(ib + 0u) >> 9) < xx.x * 8388608.0f) ? 0x3F80u : 0u;
    w |= ((float)(tf_hash(ib + 1u) >> 9) < xx.y * 8388608.0f) ? 0x3F800000u : 0u;
    return w;
}

// ---------------------------------------------------------------------------
// Kernel B0: split W1 (f32 [784][256]) into transposed bf16 hi/mid/lo
// [256][800]. EXACT: hi+mid+lo == w bitwise.
// ---------------------------------------------------------------------------
__global__ __launch_bounds__(256) void splitk_k(
        const float* __restrict__ W1, ushort* __restrict__ hiT,
        ushort* __restrict__ midT, ushort* __restrict__ loT) {
    int n = blockIdx.x;                  // 0..255
    for (int k = threadIdx.x; k < KPAD; k += 256) {
        float w = (k < IN_DIM) ? W1[k * HID + n] : 0.0f;
        uint32_t u = __float_as_uint(w);
        uint32_t hb = (u + 0x7FFFu + ((u >> 16) & 1u)) >> 16;    // RNE to bf16
        float hf = __uint_as_float(hb << 16);
        float r1 = w - hf;                                       // exact
        uint32_t u1 = __float_as_uint(r1);
        uint32_t mb = (u1 + 0x7FFFu + ((u1 >> 16) & 1u)) >> 16;  // RNE
        float mf2 = __uint_as_float(mb << 16);
        float r2 = r1 - mf2;                                     // exact
        uint32_t u2 = __float_as_uint(r2);
        uint32_t lb = (u2 + 0x7FFFu + ((u2 >> 16) & 1u)) >> 16;  // exact fit
        hiT [n * KPAD + k] = (ushort)hb;
        midT[n * KPAD + k] = (ushort)mb;
        loT [n * KPAD + k] = (ushort)lb;
    }
}

// ---------------------------------------------------------------------------
// Fused spikegen + GEMM: I_all = bernoulli(x) @ W1 + b1 (3-plane exact bf16).
// Block: 160 rows x 256 cols, 512 threads = 8 waves (2M x 4N), wave = 80x64
// = 5x4 tiles of 16x16x32. Grid 256 = 1 block/CU. A and B double-buffered;
// one __syncthreads per slab. Slab body: issue B[kw+1] global_load_lds ->
// ds_read ALL 17 cur frags -> 5x hash2 tasks + ds_write_b32 into A[nxt] ->
// 60 MFMA (register-only, interleaves with hash) -> barrier, flip.
// LDS: A bufs [0,20480), B bufs 20480 + c*49152 {hi+0, mid+16384, lo+32768}.
// ---------------------------------------------------------------------------
#define LDS_B0  20480
#define B_BUFSZ 49152
#define A_BUFSZ 10240

__global__ __launch_bounds__(512, 2) void fused_gemm_k(
        const ushort* __restrict__ hiT, const ushort* __restrict__ midT,
        const ushort* __restrict__ loT, const float* __restrict__ b1,
        const float* __restrict__ x, float* __restrict__ I_all) {
    __shared__ __align__(16) char lds[118784];   // 116 KB, 1 block/CU

    const int tid = threadIdx.x;
    const int l   = tid & 63;
    const int wv  = tid >> 6;        // 0..7
    const int wm  = wv >> 2;         // 0..1 (M half)
    const int wn  = wv & 3;          // 0..3 (N quarter)
    const int m0  = blockIdx.x * M_TILE;

    f32x4 acc[5][4] = {};

    // fragment read addressing (shared swizzle sig for A and B)
    const int q   = l >> 4;
    const int sig = q ^ (l & 3) ^ ((l >> 2) & 3);
    const int a_rd = wm * 5120 + ((l & 15) << 6) + (sig << 4);      // in A buf
    const int b_rd = (((wn << 6) + (l & 15)) << 6) + (sig << 4);    // in plane

    // ---- B staging: 1024 slots of 16B per plane, 2 per thread ----
    const ushort* hi_p[2];
    const ushort* md_p[2];
    const ushort* lo_p[2];
    int bdst[2];
#pragma unroll
    for (int i = 0; i < 2; ++i) {
        int s  = (i << 9) + tid;
        int n  = s >> 2;
        int qs = s & 3;
        int qd = qs ^ (n & 3) ^ ((n >> 2) & 3);
        size_t eoff = (size_t)n * KPAD + ((size_t)qd << 3);
        hi_p[i] = hiT  + eoff;
        md_p[i] = midT + eoff;
        lo_p[i] = loT  + eoff;
        bdst[i] = ((i << 9) + (wv << 6)) << 4;    // wave-uniform base
    }

    // ---- A expansion: 2560 hash2 tasks/slab = exactly 5 per thread. ----
    // Task tau = tid + 512*s: row = tau>>4 (0..159), pair p = tau&15;
    // computes bits {2p, 2p+1} of (row, slab)'s 32-bit word -> one u32
    // (2 bf16) at frag dword: quarter qd = (p>>2)^swz(row), dword p&3.
    int      adst[5];
    const float* txp[5];
    uint32_t tib[5];
    int      tpp[5];
#pragma unroll
    for (int s = 0; s < 5; ++s) {
        int tau = tid + (s << 9);
        int row = tau >> 4;
        int p   = tau & 15;
        int qd  = (p >> 2) ^ (row & 3) ^ ((row >> 2) & 3);
        adst[s] = (row << 6) + (qd << 4) + ((p & 3) << 2);
        int rowg = m0 + row;
        txp[s]  = x + (size_t)(rowg & (BATCH - 1)) * IN_DIM + (p << 1);
        tib[s]  = (uint32_t)rowg * (uint32_t)IN_DIM + (uint32_t)(p << 1);
        tpp[s]  = p;
    }

#define STAGE_B(koff, bbase) \
    _Pragma("unroll") \
    for (int i = 0; i < 2; ++i) { \
        __builtin_amdgcn_global_load_lds( \
            (const __attribute__((address_space(1))) void*)(hi_p[i] + (koff)), \
            (__attribute__((address_space(3))) void*)(lds + (bbase) + bdst[i]), \
            16, 0, 0); \
        __builtin_amdgcn_global_load_lds( \
            (const __attribute__((address_space(1))) void*)(md_p[i] + (koff)), \
            (__attribute__((address_space(3))) void*)(lds + (bbase) + 16384 + bdst[i]), \
            16, 0, 0); \
        __builtin_amdgcn_global_load_lds( \
            (const __attribute__((address_space(1))) void*)(lo_p[i] + (koff)), \
            (__attribute__((address_space(3))) void*)(lds + (bbase) + 32768 + bdst[i]), \
            16, 0, 0); \
    }

// hash one slab's A bits into buffer at abase. is_tail: slab 24, pairs with
// p>=8 (k>=784) stay zero (also guards the x OOB load).
#define HASH_SLAB(koff, abase, is_tail) \
    _Pragma("unroll") \
    for (int s = 0; s < 5; ++s) { \
        uint32_t w_ = 0u; \
        if (!(is_tail) || tpp[s] < 8) \
            w_ = hash2(tib[s] + (uint32_t)(koff), txp[s] + (koff)); \
        *(uint32_t*)(lds + (abase) + adst[s]) = w_; \
    }

    // ---- prologue: stage + hash slab 0 into buffers 0 ----
    STAGE_B(0, LDS_B0)
    HASH_SLAB(0, 0, false)
    __syncthreads();

    int cur = 0;
#pragma unroll 1
    for (int kw = 0; kw < KWORDS; ++kw) {
        const int nxt = cur ^ 1;

        // (1) issue next slab's B loads first (vmcnt queue fills early)
        if (kw < KWORDS - 1) {
            const int koff = (kw + 1) << 5;           // +32 elems per slab
            STAGE_B(koff, LDS_B0 + nxt * B_BUFSZ)
        }

        // (2) preload ALL cur frags: 5 A + 12 B ds_read_b128.
        // Issued before the hash -> lgkm latency hides under ~5.5K cyc of
        // hash VALU; MFMAs below are register-only.
        const char* A = lds + cur * A_BUFSZ;
        const char* B = lds + LDS_B0 + cur * B_BUFSZ;
        bf16x8 af[5];
        bf16x8 bfr[3][4];
#pragma unroll
        for (int mt = 0; mt < 5; ++mt)
            af[mt] = *(const bf16x8*)(A + a_rd + (mt << 10));
#pragma unroll
        for (int nt = 0; nt < 4; ++nt) {
            bfr[0][nt] = *(const bf16x8*)(B + b_rd + (nt << 10));
            bfr[1][nt] = *(const bf16x8*)(B + 16384 + b_rd + (nt << 10));
            bfr[2][nt] = *(const bf16x8*)(B + 32768 + b_rd + (nt << 10));
        }

        // (3) hash next slab's A bits into nxt (balanced: 10 hashes/thread)
        if (kw < KWORDS - 1) {
            const int koff = (kw + 1) << 5;
            const bool tail = (kw + 1 == KWORDS - 1);
            HASH_SLAB(koff, nxt * A_BUFSZ, tail)
        }

        // (4) compute slab kw: 5x4x3 = 60 MFMA / wave (regs only; scheduler
        // free to interleave with the hash above)
#pragma unroll
        for (int nt = 0; nt < 4; ++nt) {
#pragma unroll
            for (int mt = 0; mt < 5; ++mt) {
                acc[mt][nt] = __builtin_amdgcn_mfma_f32_16x16x32_bf16(af[mt], bfr[0][nt], acc[mt][nt], 0, 0, 0);
                acc[mt][nt] = __builtin_amdgcn_mfma_f32_16x16x32_bf16(af[mt], bfr[1][nt], acc[mt][nt], 0, 0, 0);
                acc[mt][nt] = __builtin_amdgcn_mfma_f32_16x16x32_bf16(af[mt], bfr[2][nt], acc[mt][nt], 0, 0, 0);
            }
        }

        __syncthreads();   // drains vmcnt (B nxt) + lgkm (A nxt); flip safe
        cur = nxt;
    }
#undef STAGE_B
#undef HASH_SLAB

    // --- epilogue: acc -> I_all (+ b1) ---
    const int c0 = l & 15;
    float b1v[4];
#pragma unroll
    for (int nt = 0; nt < 4; ++nt)
        b1v[nt] = b1[(wn << 6) + (nt << 4) + c0];
#pragma unroll
    for (int mt = 0; mt < 5; ++mt) {
#pragma unroll
        for (int nt = 0; nt < 4; ++nt) {
            int col = (wn << 6) + (nt << 4) + c0;
#pragma unroll
            for (int r = 0; r < 4; ++r) {
                int row = m0 + wm * 80 + (mt << 4) + (q << 2) + r;
                I_all[(size_t)row * HID + col] = acc[mt][nt][r] + b1v[nt];
            }
        }
    }
}

// ---------------------------------------------------------------------------
// Fused LIF scan + readout: per block, 4 batch rows (1024 blocks = 4/CU).
// Phase 1: thread h scans 4 rows over t (exact reference op order) -> g in
// LDS. Phase 2: wave wv -> row b0+wv, lane c<47: out = sum_h g[b][h]*Wr[h][c]
// (+ br*(1-2^-10)), h ascending — identical fmaf chain to R15.
// ---------------------------------------------------------------------------
__global__ __launch_bounds__(256) void scanout_k(
        const float* __restrict__ I_all, const float* __restrict__ Wr,
        const float* __restrict__ br, float* __restrict__ out) {
    __shared__ float gl[4 * 256];        // 4 KB
    const int tid = threadIdx.x;
    const int b0  = blockIdx.x << 2;

#pragma unroll
    for (int b = 0; b < 4; ++b) {
        const float* p = I_all + ((size_t)(b0 + b) << 8) + tid;
        float v = 0.f, ga = 0.f, wt = 0.0009765625f;   // 2^-10
#pragma unroll
        for (int t = 0; t < T_STEPS; ++t) {
            float I = p[(size_t)t * BATCH * HID];
            v = v + (I - v) * 0.5f;
            if (v >= 1.0f) { ga += wt; v = 0.f; }
            wt += wt;
        }
        gl[(b << 8) + tid] = ga;
    }
    __syncthreads();

    const int wv = tid >> 6;             // wave -> batch row b0+wv
    const int c  = tid & 63;
    if (c >= NCLS) return;
    const float* gb = &gl[wv << 8];
    float acc = 0.f;
    for (int h4 = 0; h4 < 64; ++h4) {
        float w0 = Wr[((h4 << 2) + 0) * NCLS + c];
        float w1 = Wr[((h4 << 2) + 1) * NCLS + c];
        float w2 = Wr[((h4 << 2) + 2) * NCLS + c];
        float w3 = Wr[((h4 << 2) + 3) * NCLS + c];
        float4 gg = *(const float4*)&gb[h4 << 2];
        acc = fmaf(gg.x, w0, acc);
        acc = fmaf(gg.y, w1, acc);
        acc = fmaf(gg.z, w2, acc);
        acc = fmaf(gg.w, w3, acc);
    }
    float brv = br[c] * 0.9990234375f;
    out[(b0 + wv) * NCLS + c] = acc + brv;
}

extern "C" void kernel_launch(void* const* d_in, const int* in_sizes, int n_in,
                              void* d_out, int out_size, void* d_ws, size_t ws_size,
                              hipStream_t stream) {
    const float* x  = (const float*)d_in[0];
    const float* W1 = (const float*)d_in[1];
    const float* b1 = (const float*)d_in[2];
    const float* Wr = (const float*)d_in[3];
    const float* br = (const float*)d_in[4];
    float* out = (float*)d_out;

    float*  I_all = (float*) ((char*)d_ws + WS_IALL_OFF);
    ushort* w1hi  = (ushort*)((char*)d_ws + WS_W1HI_OFF);
    ushort* w1md  = (ushort*)((char*)d_ws + WS_W1MD_OFF);
    ushort* w1lo  = (ushort*)((char*)d_ws + WS_W1LO_OFF);

    splitk_k<<<HID, 256, 0, stream>>>(W1, w1hi, w1md, w1lo);
    fused_gemm_k<<<NROWS / M_TILE, 512, 0, stream>>>(w1hi, w1md, w1lo, b1, x, I_all);
    scanout_k<<<BATCH / 4, 256, 0, stream>>>(I_all, Wr, br, out);
}